// Round 1
// baseline (526.964 us; speedup 1.0000x reference)
//
#include <hip/hip_runtime.h>
#include <hip/hip_bf16.h>

typedef __attribute__((ext_vector_type(4))) float f32x4;
typedef __attribute__((ext_vector_type(8))) short bf16x8;
typedef unsigned short u16;

#define SEQ 2048
#define HID 1024
#define NBATCH 8
#define NROWS (NBATCH * SEQ)   // 16384

// ---------- helpers ----------
__device__ __forceinline__ float b2f(u16 u) {
    union { float f; unsigned i; } x; x.i = ((unsigned)u) << 16; return x.f;
}
__device__ __forceinline__ u16 f2b(float f) {
    unsigned x = __float_as_uint(f);
    unsigned r = (x + 0x7fffu + ((x >> 16) & 1u)) >> 16;
    return (u16)r;
}
__device__ __forceinline__ void gload16(const u16* g, u16* l) {
    __builtin_amdgcn_global_load_lds(
        (const __attribute__((address_space(1))) void*)g,
        (__attribute__((address_space(3))) void*)l,
        16, 0, 0);
}

// ---------- fp32 -> bf16 convert ----------
__global__ __launch_bounds__(256)
void cvt_kernel(const float* __restrict__ src, u16* __restrict__ dst, int n) {
    int base = (blockIdx.x * 256 + threadIdx.x) * 4;
    if (base < n) {
        float4 v = *(const float4*)&src[base];
        ushort4 o;
        o.x = f2b(v.x); o.y = f2b(v.y); o.z = f2b(v.z); o.w = f2b(v.w);
        *(ushort4*)&dst[base] = o;
    }
}

// ---------- GEMM: C = A @ B^T (+bias)*scale (+resid)  ----------
// A: [M][K] bf16 K-contiguous, B: [N][K] bf16 K-contiguous.
// OUTMODE 0: bf16 normal write (ldc cols), batch offset bz*sC
// OUTMODE 1: bf16 transposed write to vT[b][col][s]  (b,s from global row)
// OUTMODE 2: fp32 write with +bias +resid (resid fp32 same layout as C)
template<int OUTMODE>
__global__ __launch_bounds__(256, 2)
void gemm_bt_kernel(const u16* __restrict__ A, const u16* __restrict__ B,
                    void* __restrict__ C,
                    const float* __restrict__ bias,
                    const float* __restrict__ resid,
                    float scale, int K,
                    long long sA, long long sB, long long sC,
                    int ldc)
{
    const int bz = blockIdx.z;
    A += (long long)bz * sA;
    B += (long long)bz * sB;

    const int tid  = threadIdx.x;
    const int lane = tid & 63;
    const int w    = tid >> 6;
    const int wm   = w >> 1, wn = w & 1;
    const int fr   = lane & 15;
    const int kg   = lane >> 4;

    const int m0 = blockIdx.y * 128;
    const int n0 = blockIdx.x * 128;

    __shared__ u16 Al[128 * 32];
    __shared__ u16 Bl[128 * 32];

    f32x4 acc[4][4] = {};

    const int nk = K >> 5;
    for (int kt = 0; kt < nk; ++kt) {
        if (kt) __syncthreads();
        const int kb = kt * 32;
#pragma unroll
        for (int r = 0; r < 2; ++r) {
            int idx = r * 256 + tid;
            int row = idx >> 2;
            int ce  = (idx & 3) * 8;
            gload16(A + (size_t)(m0 + row) * K + kb + ce, &Al[idx * 8]);
            gload16(B + (size_t)(n0 + row) * K + kb + ce, &Bl[idx * 8]);
        }
        __syncthreads();

        bf16x8 af[4], bfr[4];
#pragma unroll
        for (int m = 0; m < 4; ++m)
            af[m] = *(const bf16x8*)&Al[(wm * 64 + m * 16 + fr) * 32 + kg * 8];
#pragma unroll
        for (int n = 0; n < 4; ++n)
            bfr[n] = *(const bf16x8*)&Bl[(wn * 64 + n * 16 + fr) * 32 + kg * 8];
#pragma unroll
        for (int m = 0; m < 4; ++m)
#pragma unroll
            for (int n = 0; n < 4; ++n)
                acc[m][n] = __builtin_amdgcn_mfma_f32_16x16x32_bf16(af[m], bfr[n], acc[m][n], 0, 0, 0);
    }

    const int r0 = (lane >> 4) * 4;
    const int cc = lane & 15;
#pragma unroll
    for (int n = 0; n < 4; ++n) {
        const int gc = n0 + wn * 64 + n * 16 + cc;
        const float bv = bias ? bias[gc] : 0.0f;
#pragma unroll
        for (int m = 0; m < 4; ++m) {
            const int gr = m0 + wm * 64 + m * 16 + r0;
            if constexpr (OUTMODE == 0) {
                u16* Cb = (u16*)C + (long long)bz * sC;
#pragma unroll
                for (int r = 0; r < 4; ++r)
                    Cb[(size_t)(gr + r) * ldc + gc] = f2b((acc[m][n][r] + bv) * scale);
            } else if constexpr (OUTMODE == 1) {
                u16* Cb = (u16*)C;
                int b  = gr >> 11;
                int s0 = gr & 2047;
                ushort4 pk;
                pk.x = f2b((acc[m][n][0] + bv) * scale);
                pk.y = f2b((acc[m][n][1] + bv) * scale);
                pk.z = f2b((acc[m][n][2] + bv) * scale);
                pk.w = f2b((acc[m][n][3] + bv) * scale);
                *(ushort4*)&Cb[((size_t)b * HID + gc) * SEQ + s0] = pk;
            } else {
                float* Cf = (float*)C;
#pragma unroll
                for (int r = 0; r < 4; ++r) {
                    size_t o = (size_t)(gr + r) * ldc + gc;
                    Cf[o] = acc[m][n][r] + bv + resid[o];
                }
            }
        }
    }
}

// ---------- row softmax, in-place, bf16, row length 2048 ----------
__global__ __launch_bounds__(256)
void softmax_kernel(u16* __restrict__ sc) {
    const size_t row = blockIdx.x;
    u16* p = sc + row * 2048;
    const int tid = threadIdx.x;
    const int lane = tid & 63;
    const int w = tid >> 6;

    float v[8];
    ushort4 ua = *(const ushort4*)&p[tid * 8];
    ushort4 ub = *(const ushort4*)&p[tid * 8 + 4];
    v[0] = b2f(ua.x); v[1] = b2f(ua.y); v[2] = b2f(ua.z); v[3] = b2f(ua.w);
    v[4] = b2f(ub.x); v[5] = b2f(ub.y); v[6] = b2f(ub.z); v[7] = b2f(ub.w);

    float mx = v[0];
#pragma unroll
    for (int j = 1; j < 8; ++j) mx = fmaxf(mx, v[j]);
#pragma unroll
    for (int o = 32; o; o >>= 1) mx = fmaxf(mx, __shfl_xor(mx, o));

    __shared__ float red[8];
    if (!lane) red[w] = mx;
    __syncthreads();
    mx = fmaxf(fmaxf(red[0], red[1]), fmaxf(red[2], red[3]));

    float s = 0.f;
#pragma unroll
    for (int j = 0; j < 8; ++j) { v[j] = __expf(v[j] - mx); s += v[j]; }
#pragma unroll
    for (int o = 32; o; o >>= 1) s += __shfl_xor(s, o);
    if (!lane) red[4 + w] = s;
    __syncthreads();
    s = red[4] + red[5] + red[6] + red[7];
    float inv = 1.0f / s;

    ushort4 oa, ob;
    oa.x = f2b(v[0] * inv); oa.y = f2b(v[1] * inv); oa.z = f2b(v[2] * inv); oa.w = f2b(v[3] * inv);
    ob.x = f2b(v[4] * inv); ob.y = f2b(v[5] * inv); ob.z = f2b(v[6] * inv); ob.w = f2b(v[7] * inv);
    *(ushort4*)&p[tid * 8]     = oa;
    *(ushort4*)&p[tid * 8 + 4] = ob;
}

// ---------- in-place LayerNorm over rows of 1024 fp32 ----------
__global__ __launch_bounds__(256)
void layernorm_kernel(float* __restrict__ y,
                      const float* __restrict__ gamma,
                      const float* __restrict__ beta) {
    const size_t row = blockIdx.x;
    float* p = y + row * 1024;
    const int tid = threadIdx.x;
    const int lane = tid & 63;
    const int w = tid >> 6;

    float4 v = *(const float4*)&p[tid * 4];
    float s = v.x + v.y + v.z + v.w;
    float q = v.x * v.x + v.y * v.y + v.z * v.z + v.w * v.w;
#pragma unroll
    for (int o = 32; o; o >>= 1) { s += __shfl_xor(s, o); q += __shfl_xor(q, o); }

    __shared__ float red[16];
    if (!lane) { red[w] = s; red[8 + w] = q; }
    __syncthreads();
    s = red[0] + red[1] + red[2] + red[3];
    q = red[8] + red[9] + red[10] + red[11];

    const float mu  = s * (1.0f / 1024.0f);
    const float var = q * (1.0f / 1024.0f) - mu * mu;
    const float rs  = rsqrtf(var + 1e-5f);

    float4 g  = *(const float4*)&gamma[tid * 4];
    float4 be = *(const float4*)&beta[tid * 4];
    float4 o;
    o.x = (v.x - mu) * rs * g.x + be.x;
    o.y = (v.y - mu) * rs * g.y + be.y;
    o.z = (v.z - mu) * rs * g.z + be.z;
    o.w = (v.w - mu) * rs * g.w + be.w;
    *(float4*)&p[tid * 4] = o;
}

extern "C" void kernel_launch(void* const* d_in, const int* in_sizes, int n_in,
                              void* d_out, int out_size, void* d_ws, size_t ws_size,
                              hipStream_t stream) {
    const float* x     = (const float*)d_in[0];
    const float* Wq    = (const float*)d_in[1];
    const float* bq    = (const float*)d_in[2];
    const float* Wk    = (const float*)d_in[3];
    const float* bk    = (const float*)d_in[4];
    const float* Wv    = (const float*)d_in[5];
    const float* bv    = (const float*)d_in[6];
    const float* Wp    = (const float*)d_in[7];
    const float* bp    = (const float*)d_in[8];
    const float* gamma = (const float*)d_in[9];
    const float* beta  = (const float*)d_in[10];
    float* out = (float*)d_out;

    char* ws = (char*)d_ws;
    u16* xb     = (u16*)(ws + 0);            // 33,554,432 B
    u16* qb     = (u16*)(ws + 33554432);
    u16* kb     = (u16*)(ws + 67108864);
    u16* vT     = (u16*)(ws + 100663296);    // [8][1024][2048]
    u16* ctx    = (u16*)(ws + 134217728);
    u16* wqb    = (u16*)(ws + 167772160);
    u16* wkb    = (u16*)(ws + 169869312);
    u16* wvb    = (u16*)(ws + 171966464);
    u16* wpb    = (u16*)(ws + 174063616);
    u16* scores = (u16*)(ws + 176160768);    // 67,108,864 B -> total ~243 MB

    // converts
    cvt_kernel<<<16384, 256, 0, stream>>>(x,  xb,  NROWS * HID);
    cvt_kernel<<<1024, 256, 0, stream>>>(Wq, wqb, HID * HID);
    cvt_kernel<<<1024, 256, 0, stream>>>(Wk, wkb, HID * HID);
    cvt_kernel<<<1024, 256, 0, stream>>>(Wv, wvb, HID * HID);
    cvt_kernel<<<1024, 256, 0, stream>>>(Wp, wpb, HID * HID);

    dim3 blk(256);
    // q/k/v projections  (q folded with 1/sqrt(H)=1/32)
    gemm_bt_kernel<0><<<dim3(8, 128, 1), blk, 0, stream>>>(xb, wqb, qb, bq, nullptr, 0.03125f, HID, 0, 0, 0, HID);
    gemm_bt_kernel<0><<<dim3(8, 128, 1), blk, 0, stream>>>(xb, wkb, kb, bk, nullptr, 1.0f,     HID, 0, 0, 0, HID);
    gemm_bt_kernel<1><<<dim3(8, 128, 1), blk, 0, stream>>>(xb, wvb, vT, bv, nullptr, 1.0f,     HID, 0, 0, 0, 0);

    // scores = q' @ k^T  (per batch)
    gemm_bt_kernel<0><<<dim3(16, 16, 8), blk, 0, stream>>>(
        qb, kb, scores, nullptr, nullptr, 1.0f, HID,
        (long long)SEQ * HID, (long long)SEQ * HID, (long long)SEQ * SEQ, SEQ);

    // softmax rows
    softmax_kernel<<<NROWS, 256, 0, stream>>>(scores);

    // context = attn @ v   (B = vT, K-contiguous)
    gemm_bt_kernel<0><<<dim3(8, 16, 8), blk, 0, stream>>>(
        scores, vT, ctx, nullptr, nullptr, 1.0f, SEQ,
        (long long)SEQ * SEQ, (long long)HID * SEQ, (long long)SEQ * HID, HID);

    // out = ctx @ Wp^T + bp + x   (fp32 into d_out)
    gemm_bt_kernel<2><<<dim3(8, 128, 1), blk, 0, stream>>>(ctx, wpb, out, bp, x, 1.0f, HID, 0, 0, 0, HID);

    // LayerNorm in place on d_out
    layernorm_kernel<<<NROWS, 256, 0, stream>>>(out, gamma, beta);
}

// Round 2
// 459.424 us; speedup vs baseline: 1.1470x; 1.1470x over previous
//
#include <hip/hip_runtime.h>
#include <hip/hip_bf16.h>

typedef __attribute__((ext_vector_type(4))) float f32x4;
typedef __attribute__((ext_vector_type(8))) short bf16x8;
typedef unsigned short u16;

#define SEQ 2048
#define HID 1024
#define NBATCH 8
#define NROWS (NBATCH * SEQ)   // 16384

// ---------- helpers ----------
__device__ __forceinline__ float b2f(u16 u) {
    union { float f; unsigned i; } x; x.i = ((unsigned)u) << 16; return x.f;
}
__device__ __forceinline__ u16 f2b(float f) {
    unsigned x = __float_as_uint(f);
    unsigned r = (x + 0x7fffu + ((x >> 16) & 1u)) >> 16;
    return (u16)r;
}
__device__ __forceinline__ void gload16(const u16* g, u16* l) {
    __builtin_amdgcn_global_load_lds(
        (const __attribute__((address_space(1))) void*)g,
        (__attribute__((address_space(3))) void*)l,
        16, 0, 0);
}

// ---------- fp32 -> bf16 convert ----------
__global__ __launch_bounds__(256)
void cvt_kernel(const float* __restrict__ src, u16* __restrict__ dst, int n) {
    int base = (blockIdx.x * 256 + threadIdx.x) * 4;
    if (base < n) {
        float4 v = *(const float4*)&src[base];
        ushort4 o;
        o.x = f2b(v.x); o.y = f2b(v.y); o.z = f2b(v.z); o.w = f2b(v.w);
        *(ushort4*)&dst[base] = o;
    }
}

// ---------- GEMM: C = A @ B^T (+bias)*scale (+resid)  ----------
// A: [M][K] bf16 K-contiguous, B: [N][K] bf16 K-contiguous.
// OUTMODE 0: bf16 normal write (ldc cols), batch offset bz*sC
// OUTMODE 1: bf16 transposed write to vT[b][col][s]  (b,s from global row)
// OUTMODE 2: fp32 write with +bias +resid (resid fp32 same layout as C)
template<int OUTMODE>
__global__ __launch_bounds__(256, 2)
void gemm_bt_kernel(const u16* __restrict__ A, const u16* __restrict__ B,
                    void* __restrict__ C,
                    const float* __restrict__ bias,
                    const float* __restrict__ resid,
                    float scale, int K,
                    long long sA, long long sB, long long sC,
                    int ldc)
{
    // ---- XCD-bijective block swizzle (T1): each XCD gets a contiguous
    // chunk of work-ids; consecutive work-ids (n-dim fastest) share A panels.
    const unsigned nwg = gridDim.x * gridDim.y * gridDim.z;
    const unsigned bid = blockIdx.x + gridDim.x * (blockIdx.y + gridDim.y * blockIdx.z);
    const unsigned work = (bid & 7u) * (nwg >> 3) + (bid >> 3);
    const unsigned bx = work % gridDim.x;
    const unsigned rem = work / gridDim.x;
    const unsigned by = rem % gridDim.y;
    const unsigned bz = rem / gridDim.y;

    A += (long long)bz * sA;
    B += (long long)bz * sB;

    const int tid  = threadIdx.x;
    const int lane = tid & 63;
    const int w    = tid >> 6;
    const int wm   = w >> 1, wn = w & 1;
    const int fr   = lane & 15;
    const int kg   = lane >> 4;

    const int m0 = by * 128;
    const int n0 = bx * 128;

    __shared__ u16 Al[128 * 32];
    __shared__ u16 Bl[128 * 32];

    f32x4 acc[4][4] = {};

    const int nk = K >> 5;
    for (int kt = 0; kt < nk; ++kt) {
        if (kt) __syncthreads();
        const int kb = kt * 32;
#pragma unroll
        for (int r = 0; r < 2; ++r) {
            int idx = r * 256 + tid;
            int row = idx >> 2;
            int ce  = (idx & 3) * 8;
            gload16(A + (size_t)(m0 + row) * K + kb + ce, &Al[idx * 8]);
            gload16(B + (size_t)(n0 + row) * K + kb + ce, &Bl[idx * 8]);
        }
        __syncthreads();

        bf16x8 af[4], bfr[4];
#pragma unroll
        for (int m = 0; m < 4; ++m)
            af[m] = *(const bf16x8*)&Al[(wm * 64 + m * 16 + fr) * 32 + kg * 8];
#pragma unroll
        for (int n = 0; n < 4; ++n)
            bfr[n] = *(const bf16x8*)&Bl[(wn * 64 + n * 16 + fr) * 32 + kg * 8];
#pragma unroll
        for (int m = 0; m < 4; ++m)
#pragma unroll
            for (int n = 0; n < 4; ++n)
                acc[m][n] = __builtin_amdgcn_mfma_f32_16x16x32_bf16(af[m], bfr[n], acc[m][n], 0, 0, 0);
    }

    const int r0 = (lane >> 4) * 4;
    const int cc = lane & 15;
#pragma unroll
    for (int n = 0; n < 4; ++n) {
        const int gc = n0 + wn * 64 + n * 16 + cc;
        const float bv = bias ? bias[gc] : 0.0f;
#pragma unroll
        for (int m = 0; m < 4; ++m) {
            const int gr = m0 + wm * 64 + m * 16 + r0;
            if constexpr (OUTMODE == 0) {
                u16* Cb = (u16*)C + (long long)bz * sC;
#pragma unroll
                for (int r = 0; r < 4; ++r)
                    Cb[(size_t)(gr + r) * ldc + gc] = f2b((acc[m][n][r] + bv) * scale);
            } else if constexpr (OUTMODE == 1) {
                u16* Cb = (u16*)C;
                int b  = gr >> 11;
                int s0 = gr & 2047;
                ushort4 pk;
                pk.x = f2b((acc[m][n][0] + bv) * scale);
                pk.y = f2b((acc[m][n][1] + bv) * scale);
                pk.z = f2b((acc[m][n][2] + bv) * scale);
                pk.w = f2b((acc[m][n][3] + bv) * scale);
                *(ushort4*)&Cb[((size_t)b * HID + gc) * SEQ + s0] = pk;
            } else {
                float* Cf = (float*)C;
#pragma unroll
                for (int r = 0; r < 4; ++r) {
                    size_t o = (size_t)(gr + r) * ldc + gc;
                    Cf[o] = acc[m][n][r] + bv + resid[o];
                }
            }
        }
    }
}

// ---------- row softmax, in-place, bf16, row length 2048 ----------
__global__ __launch_bounds__(256)
void softmax_kernel(u16* __restrict__ sc) {
    const size_t row = blockIdx.x;
    u16* p = sc + row * 2048;
    const int tid = threadIdx.x;
    const int lane = tid & 63;
    const int w = tid >> 6;

    float v[8];
    ushort4 ua = *(const ushort4*)&p[tid * 8];
    ushort4 ub = *(const ushort4*)&p[tid * 8 + 4];
    v[0] = b2f(ua.x); v[1] = b2f(ua.y); v[2] = b2f(ua.z); v[3] = b2f(ua.w);
    v[4] = b2f(ub.x); v[5] = b2f(ub.y); v[6] = b2f(ub.z); v[7] = b2f(ub.w);

    float mx = v[0];
#pragma unroll
    for (int j = 1; j < 8; ++j) mx = fmaxf(mx, v[j]);
#pragma unroll
    for (int o = 32; o; o >>= 1) mx = fmaxf(mx, __shfl_xor(mx, o));

    __shared__ float red[8];
    if (!lane) red[w] = mx;
    __syncthreads();
    mx = fmaxf(fmaxf(red[0], red[1]), fmaxf(red[2], red[3]));

    float s = 0.f;
#pragma unroll
    for (int j = 0; j < 8; ++j) { v[j] = __expf(v[j] - mx); s += v[j]; }
#pragma unroll
    for (int o = 32; o; o >>= 1) s += __shfl_xor(s, o);
    if (!lane) red[4 + w] = s;
    __syncthreads();
    s = red[4] + red[5] + red[6] + red[7];
    float inv = 1.0f / s;

    ushort4 oa, ob;
    oa.x = f2b(v[0] * inv); oa.y = f2b(v[1] * inv); oa.z = f2b(v[2] * inv); oa.w = f2b(v[3] * inv);
    ob.x = f2b(v[4] * inv); ob.y = f2b(v[5] * inv); ob.z = f2b(v[6] * inv); ob.w = f2b(v[7] * inv);
    *(ushort4*)&p[tid * 8]     = oa;
    *(ushort4*)&p[tid * 8 + 4] = ob;
}

// ---------- in-place LayerNorm over rows of 1024 fp32 ----------
__global__ __launch_bounds__(256)
void layernorm_kernel(float* __restrict__ y,
                      const float* __restrict__ gamma,
                      const float* __restrict__ beta) {
    const size_t row = blockIdx.x;
    float* p = y + row * 1024;
    const int tid = threadIdx.x;
    const int lane = tid & 63;
    const int w = tid >> 6;

    float4 v = *(const float4*)&p[tid * 4];
    float s = v.x + v.y + v.z + v.w;
    float q = v.x * v.x + v.y * v.y + v.z * v.z + v.w * v.w;
#pragma unroll
    for (int o = 32; o; o >>= 1) { s += __shfl_xor(s, o); q += __shfl_xor(q, o); }

    __shared__ float red[16];
    if (!lane) { red[w] = s; red[8 + w] = q; }
    __syncthreads();
    s = red[0] + red[1] + red[2] + red[3];
    q = red[8] + red[9] + red[10] + red[11];

    const float mu  = s * (1.0f / 1024.0f);
    const float var = q * (1.0f / 1024.0f) - mu * mu;
    const float rs  = rsqrtf(var + 1e-5f);

    float4 g  = *(const float4*)&gamma[tid * 4];
    float4 be = *(const float4*)&beta[tid * 4];
    float4 o;
    o.x = (v.x - mu) * rs * g.x + be.x;
    o.y = (v.y - mu) * rs * g.y + be.y;
    o.z = (v.z - mu) * rs * g.z + be.z;
    o.w = (v.w - mu) * rs * g.w + be.w;
    *(float4*)&p[tid * 4] = o;
}

extern "C" void kernel_launch(void* const* d_in, const int* in_sizes, int n_in,
                              void* d_out, int out_size, void* d_ws, size_t ws_size,
                              hipStream_t stream) {
    const float* x     = (const float*)d_in[0];
    const float* Wq    = (const float*)d_in[1];
    const float* bq    = (const float*)d_in[2];
    const float* Wk    = (const float*)d_in[3];
    const float* bk    = (const float*)d_in[4];
    const float* Wv    = (const float*)d_in[5];
    const float* bv    = (const float*)d_in[6];
    const float* Wp    = (const float*)d_in[7];
    const float* bp    = (const float*)d_in[8];
    const float* gamma = (const float*)d_in[9];
    const float* beta  = (const float*)d_in[10];
    float* out = (float*)d_out;

    char* ws = (char*)d_ws;
    u16* xb     = (u16*)(ws + 0);            // 33,554,432 B
    u16* qb     = (u16*)(ws + 33554432);
    u16* kb     = (u16*)(ws + 67108864);
    u16* vT     = (u16*)(ws + 100663296);    // [8][1024][2048]
    u16* ctx    = (u16*)(ws + 134217728);
    u16* wqb    = (u16*)(ws + 167772160);
    u16* wkb    = (u16*)(ws + 169869312);
    u16* wvb    = (u16*)(ws + 171966464);
    u16* wpb    = (u16*)(ws + 174063616);
    u16* scores = (u16*)(ws + 176160768);    // 67,108,864 B -> total ~243 MB

    // converts
    cvt_kernel<<<16384, 256, 0, stream>>>(x,  xb,  NROWS * HID);
    cvt_kernel<<<1024, 256, 0, stream>>>(Wq, wqb, HID * HID);
    cvt_kernel<<<1024, 256, 0, stream>>>(Wk, wkb, HID * HID);
    cvt_kernel<<<1024, 256, 0, stream>>>(Wv, wvb, HID * HID);
    cvt_kernel<<<1024, 256, 0, stream>>>(Wp, wpb, HID * HID);

    dim3 blk(256);
    // q/k/v projections  (q folded with 1/sqrt(H)=1/32)
    gemm_bt_kernel<0><<<dim3(8, 128, 1), blk, 0, stream>>>(xb, wqb, qb, bq, nullptr, 0.03125f, HID, 0, 0, 0, HID);
    gemm_bt_kernel<0><<<dim3(8, 128, 1), blk, 0, stream>>>(xb, wkb, kb, bk, nullptr, 1.0f,     HID, 0, 0, 0, HID);
    gemm_bt_kernel<1><<<dim3(8, 128, 1), blk, 0, stream>>>(xb, wvb, vT, bv, nullptr, 1.0f,     HID, 0, 0, 0, 0);

    // scores = q' @ k^T  (per batch)
    gemm_bt_kernel<0><<<dim3(16, 16, 8), blk, 0, stream>>>(
        qb, kb, scores, nullptr, nullptr, 1.0f, HID,
        (long long)SEQ * HID, (long long)SEQ * HID, (long long)SEQ * SEQ, SEQ);

    // softmax rows
    softmax_kernel<<<NROWS, 256, 0, stream>>>(scores);

    // context = attn @ v   (B = vT, K-contiguous)
    gemm_bt_kernel<0><<<dim3(8, 16, 8), blk, 0, stream>>>(
        scores, vT, ctx, nullptr, nullptr, 1.0f, SEQ,
        (long long)SEQ * SEQ, (long long)HID * SEQ, (long long)SEQ * HID, HID);

    // out = ctx @ Wp^T + bp + x   (fp32 into d_out)
    gemm_bt_kernel<2><<<dim3(8, 128, 1), blk, 0, stream>>>(ctx, wpb, out, bp, x, 1.0f, HID, 0, 0, 0, HID);

    // LayerNorm in place on d_out
    layernorm_kernel<<<NROWS, 256, 0, stream>>>(out, gamma, beta);
}

// Round 3
// 444.875 us; speedup vs baseline: 1.1845x; 1.0327x over previous
//
#include <hip/hip_runtime.h>
#include <hip/hip_bf16.h>

typedef __attribute__((ext_vector_type(4))) float f32x4;
typedef __attribute__((ext_vector_type(8))) short bf16x8;
typedef unsigned short u16;

#define SEQ 2048
#define HID 1024
#define NROWS 16384

// ---------- helpers ----------
__device__ __forceinline__ float b2f(u16 u) {
    union { float f; unsigned i; } x; x.i = ((unsigned)u) << 16; return x.f;
}
__device__ __forceinline__ u16 f2b(float f) {
    unsigned x = __float_as_uint(f);
    unsigned r = (x + 0x7fffu + ((x >> 16) & 1u)) >> 16;
    return (u16)r;
}
__device__ __forceinline__ void gload16(const u16* g, u16* l) {
    __builtin_amdgcn_global_load_lds(
        (const __attribute__((address_space(1))) void*)g,
        (__attribute__((address_space(3))) void*)l,
        16, 0, 0);
}

// ---------- fp32 -> bf16 convert ----------
__global__ __launch_bounds__(256)
void cvt_kernel(const float* __restrict__ src, u16* __restrict__ dst, int n) {
    int base = (blockIdx.x * 256 + threadIdx.x) * 4;
    if (base < n) {
        float4 v = *(const float4*)&src[base];
        ushort4 o;
        o.x = f2b(v.x); o.y = f2b(v.y); o.z = f2b(v.z); o.w = f2b(v.w);
        *(ushort4*)&dst[base] = o;
    }
}

// ---------- GEMM: C = A @ B^T (+bias)*scale (+resid) ----------
// 256x256 tile, BK=64, 512 threads (8 waves, 2Mx4N), per-wave 128x64 out.
// 2-buffer LDS pipeline, counted vmcnt (T3+T4), XOR-swizzled LDS (T2, rule 21:
// linear gload_lds dest + inverse-swizzled global source + swizzled read).
// A: [M][K] bf16 K-contiguous, B: [N][K] bf16 K-contiguous.
// OUTMODE 0: bf16 write (ldc cols), batch offset bz*sC
// OUTMODE 1: bf16 transposed write to vT[b][col][s]
// OUTMODE 2: fp32 write with +bias +resid
template<int OUTMODE>
__global__ __launch_bounds__(512, 2)
void gemm_bt_kernel(const u16* __restrict__ A, const u16* __restrict__ B,
                    void* __restrict__ C,
                    const float* __restrict__ bias,
                    const float* __restrict__ resid,
                    float scale, int K,
                    long long sA, long long sB, long long sC,
                    int ldc)
{
    // ---- XCD-bijective block swizzle (T1); all grids have nwg % 8 == 0.
    const unsigned nwg = gridDim.x * gridDim.y * gridDim.z;
    const unsigned bid = blockIdx.x + gridDim.x * (blockIdx.y + gridDim.y * blockIdx.z);
    const unsigned work = (bid & 7u) * (nwg >> 3) + (bid >> 3);
    const unsigned bx = work % gridDim.x;
    const unsigned rem = work / gridDim.x;
    const unsigned by = rem % gridDim.y;
    const unsigned bz = rem / gridDim.y;

    A += (long long)bz * sA;
    B += (long long)bz * sB;

    const int tid  = threadIdx.x;
    const int lane = tid & 63;
    const int w    = tid >> 6;
    const int wm   = w >> 2;      // 0..1 : 128-row M half
    const int wn   = w & 3;       // 0..3 : 64-col N quarter
    const int fr   = lane & 15;
    const int kg   = lane >> 4;

    const int m0 = by * 256;
    const int n0 = bx * 256;

    // 2 buffers x (A 256x64 + B 256x64) bf16 = 128 KiB
    __shared__ u16 lds[65536];

    f32x4 acc[8][4] = {};

    const int nk = K >> 6;

    // stage tile tt into buffer bsel. Linear LDS dest (gload_lds requirement),
    // inverse-swizzled global source column: cb ^= ((row&7)<<4) bytes.
    auto STAGE = [&](int tt, int bsel) {
        const int kb = tt << 6;
        u16* Al = &lds[bsel * 32768];
        u16* Bl = Al + 16384;
#pragma unroll
        for (int j = 0; j < 4; ++j) {
            const int idx = j * 512 + tid;
            const int r   = idx >> 3;                       // 0..255
            const int cbs = (((tid & 7) << 4) ^ ((r & 7) << 4)) >> 1; // u16 col
            gload16(A + (size_t)(m0 + r) * K + kb + cbs, &Al[idx * 8]);
            gload16(B + (size_t)(n0 + r) * K + kb + cbs, &Bl[idx * 8]);
        }
    };

    // prologue: tiles 0 and 1 in flight (16 loads outstanding per thread)
    STAGE(0, 0);
    STAGE(1, 1);

    const int swz = (fr & 7) << 3;   // u16-unit XOR for reads

    for (int t = 0; t < nk; ++t) {
        // wait: all loads except the newest 8 (= tile t+1) have landed
        if (t + 1 < nk) asm volatile("s_waitcnt vmcnt(8)" ::: "memory");
        else            asm volatile("s_waitcnt vmcnt(0)" ::: "memory");
        __builtin_amdgcn_s_barrier();   // tile t visible to all waves

        const u16* Al = &lds[(t & 1) * 32768];
        const u16* Bl = Al + 16384;

#pragma unroll
        for (int ks = 0; ks < 2; ++ks) {
            const int colbase = (ks * 32 + kg * 8);
            bf16x8 af[8];
#pragma unroll
            for (int m = 0; m < 8; ++m)
                af[m] = *(const bf16x8*)&Al[(wm * 128 + m * 16 + fr) * 64 + (colbase ^ swz)];
            bf16x8 bfr[4];
#pragma unroll
            for (int n = 0; n < 4; ++n)
                bfr[n] = *(const bf16x8*)&Bl[(wn * 64 + n * 16 + fr) * 64 + (colbase ^ swz)];
#pragma unroll
            for (int m = 0; m < 8; ++m)
#pragma unroll
                for (int n = 0; n < 4; ++n)
                    acc[m][n] = __builtin_amdgcn_mfma_f32_16x16x32_bf16(af[m], bfr[n], acc[m][n], 0, 0, 0);
        }

        __builtin_amdgcn_s_barrier();   // all reads of buf[t&1] done
        if (t + 2 < nk) STAGE(t + 2, t & 1);  // refill just-freed buffer
    }

    // ---- epilogue ----
    const int r0 = (lane >> 4) * 4;
    const int cc = lane & 15;
#pragma unroll
    for (int n = 0; n < 4; ++n) {
        const int gc = n0 + wn * 64 + n * 16 + cc;
        const float bv = bias ? bias[gc] : 0.0f;
#pragma unroll
        for (int m = 0; m < 8; ++m) {
            const int gr = m0 + wm * 128 + m * 16 + r0;
            if constexpr (OUTMODE == 0) {
                u16* Cb = (u16*)C + (long long)bz * sC;
#pragma unroll
                for (int r = 0; r < 4; ++r)
                    Cb[(size_t)(gr + r) * ldc + gc] = f2b((acc[m][n][r] + bv) * scale);
            } else if constexpr (OUTMODE == 1) {
                u16* Cb = (u16*)C;
                int b  = gr >> 11;
                int s0 = gr & 2047;
                ushort4 pk;
                pk.x = f2b((acc[m][n][0] + bv) * scale);
                pk.y = f2b((acc[m][n][1] + bv) * scale);
                pk.z = f2b((acc[m][n][2] + bv) * scale);
                pk.w = f2b((acc[m][n][3] + bv) * scale);
                *(ushort4*)&Cb[((size_t)b * HID + gc) * SEQ + s0] = pk;
            } else {
                float* Cf = (float*)C;
#pragma unroll
                for (int r = 0; r < 4; ++r) {
                    size_t o = (size_t)(gr + r) * ldc + gc;
                    Cf[o] = acc[m][n][r] + bv + resid[o];
                }
            }
        }
    }
}

// ---------- row softmax, in-place, bf16, row length 2048 ----------
__global__ __launch_bounds__(256)
void softmax_kernel(u16* __restrict__ sc) {
    const size_t row = blockIdx.x;
    u16* p = sc + row * 2048;
    const int tid = threadIdx.x;
    const int lane = tid & 63;
    const int w = tid >> 6;

    float v[8];
    ushort4 ua = *(const ushort4*)&p[tid * 8];
    ushort4 ub = *(const ushort4*)&p[tid * 8 + 4];
    v[0] = b2f(ua.x); v[1] = b2f(ua.y); v[2] = b2f(ua.z); v[3] = b2f(ua.w);
    v[4] = b2f(ub.x); v[5] = b2f(ub.y); v[6] = b2f(ub.z); v[7] = b2f(ub.w);

    float mx = v[0];
#pragma unroll
    for (int j = 1; j < 8; ++j) mx = fmaxf(mx, v[j]);
#pragma unroll
    for (int o = 32; o; o >>= 1) mx = fmaxf(mx, __shfl_xor(mx, o));

    __shared__ float red[8];
    if (!lane) red[w] = mx;
    __syncthreads();
    mx = fmaxf(fmaxf(red[0], red[1]), fmaxf(red[2], red[3]));

    float s = 0.f;
#pragma unroll
    for (int j = 0; j < 8; ++j) { v[j] = __expf(v[j] - mx); s += v[j]; }
#pragma unroll
    for (int o = 32; o; o >>= 1) s += __shfl_xor(s, o);
    if (!lane) red[4 + w] = s;
    __syncthreads();
    s = red[4] + red[5] + red[6] + red[7];
    float inv = 1.0f / s;

    ushort4 oa, ob;
    oa.x = f2b(v[0] * inv); oa.y = f2b(v[1] * inv); oa.z = f2b(v[2] * inv); oa.w = f2b(v[3] * inv);
    ob.x = f2b(v[4] * inv); ob.y = f2b(v[5] * inv); ob.z = f2b(v[6] * inv); ob.w = f2b(v[7] * inv);
    *(ushort4*)&p[tid * 8]     = oa;
    *(ushort4*)&p[tid * 8 + 4] = ob;
}

// ---------- in-place LayerNorm over rows of 1024 fp32 ----------
__global__ __launch_bounds__(256)
void layernorm_kernel(float* __restrict__ y,
                      const float* __restrict__ gamma,
                      const float* __restrict__ beta) {
    const size_t row = blockIdx.x;
    float* p = y + row * 1024;
    const int tid = threadIdx.x;
    const int lane = tid & 63;
    const int w = tid >> 6;

    float4 v = *(const float4*)&p[tid * 4];
    float s = v.x + v.y + v.z + v.w;
    float q = v.x * v.x + v.y * v.y + v.z * v.z + v.w * v.w;
#pragma unroll
    for (int o = 32; o; o >>= 1) { s += __shfl_xor(s, o); q += __shfl_xor(q, o); }

    __shared__ float red[16];
    if (!lane) { red[w] = s; red[8 + w] = q; }
    __syncthreads();
    s = red[0] + red[1] + red[2] + red[3];
    q = red[8] + red[9] + red[10] + red[11];

    const float mu  = s * (1.0f / 1024.0f);
    const float var = q * (1.0f / 1024.0f) - mu * mu;
    const float rs  = rsqrtf(var + 1e-5f);

    float4 g  = *(const float4*)&gamma[tid * 4];
    float4 be = *(const float4*)&beta[tid * 4];
    float4 o;
    o.x = (v.x - mu) * rs * g.x + be.x;
    o.y = (v.y - mu) * rs * g.y + be.y;
    o.z = (v.z - mu) * rs * g.z + be.z;
    o.w = (v.w - mu) * rs * g.w + be.w;
    *(float4*)&p[tid * 4] = o;
}

extern "C" void kernel_launch(void* const* d_in, const int* in_sizes, int n_in,
                              void* d_out, int out_size, void* d_ws, size_t ws_size,
                              hipStream_t stream) {
    const float* x     = (const float*)d_in[0];
    const float* Wq    = (const float*)d_in[1];
    const float* bq    = (const float*)d_in[2];
    const float* Wk    = (const float*)d_in[3];
    const float* bk    = (const float*)d_in[4];
    const float* Wv    = (const float*)d_in[5];
    const float* bv    = (const float*)d_in[6];
    const float* Wp    = (const float*)d_in[7];
    const float* bp    = (const float*)d_in[8];
    const float* gamma = (const float*)d_in[9];
    const float* beta  = (const float*)d_in[10];
    float* out = (float*)d_out;

    char* ws = (char*)d_ws;
    u16* xb     = (u16*)(ws + 0);            // 33,554,432 B
    u16* qb     = (u16*)(ws + 33554432);
    u16* kb     = (u16*)(ws + 67108864);
    u16* vT     = (u16*)(ws + 100663296);    // [8][1024][2048]
    u16* ctx    = (u16*)(ws + 134217728);
    u16* wqb    = (u16*)(ws + 167772160);
    u16* wkb    = (u16*)(ws + 169869312);
    u16* wvb    = (u16*)(ws + 171966464);
    u16* wpb    = (u16*)(ws + 174063616);
    u16* scores = (u16*)(ws + 176160768);    // 67,108,864 B -> total ~243 MB

    // converts
    cvt_kernel<<<16384, 256, 0, stream>>>(x,  xb,  NROWS * HID);
    cvt_kernel<<<1024, 256, 0, stream>>>(Wq, wqb, HID * HID);
    cvt_kernel<<<1024, 256, 0, stream>>>(Wk, wkb, HID * HID);
    cvt_kernel<<<1024, 256, 0, stream>>>(Wv, wvb, HID * HID);
    cvt_kernel<<<1024, 256, 0, stream>>>(Wp, wpb, HID * HID);

    dim3 blk(512);
    // q/k/v projections  (q folded with 1/sqrt(H)=1/32)
    gemm_bt_kernel<0><<<dim3(4, 64, 1), blk, 0, stream>>>(xb, wqb, qb, bq, nullptr, 0.03125f, HID, 0, 0, 0, HID);
    gemm_bt_kernel<0><<<dim3(4, 64, 1), blk, 0, stream>>>(xb, wkb, kb, bk, nullptr, 1.0f,     HID, 0, 0, 0, HID);
    gemm_bt_kernel<1><<<dim3(4, 64, 1), blk, 0, stream>>>(xb, wvb, vT, bv, nullptr, 1.0f,     HID, 0, 0, 0, 0);

    // scores = q' @ k^T  (per batch)
    gemm_bt_kernel<0><<<dim3(8, 8, 8), blk, 0, stream>>>(
        qb, kb, scores, nullptr, nullptr, 1.0f, HID,
        (long long)SEQ * HID, (long long)SEQ * HID, (long long)SEQ * SEQ, SEQ);

    // softmax rows
    softmax_kernel<<<NROWS, 256, 0, stream>>>(scores);

    // context = attn @ v   (B = vT, K-contiguous)
    gemm_bt_kernel<0><<<dim3(4, 8, 8), blk, 0, stream>>>(
        scores, vT, ctx, nullptr, nullptr, 1.0f, SEQ,
        (long long)SEQ * SEQ, (long long)HID * SEQ, (long long)SEQ * HID, HID);

    // out = ctx @ Wp^T + bp + x   (fp32 into d_out)
    gemm_bt_kernel<2><<<dim3(4, 64, 1), blk, 0, stream>>>(ctx, wpb, out, bp, x, 1.0f, HID, 0, 0, 0, HID);

    // LayerNorm in place on d_out
    layernorm_kernel<<<NROWS, 256, 0, stream>>>(out, gamma, beta);
}

// Round 4
// 373.603 us; speedup vs baseline: 1.4105x; 1.1908x over previous
//
#include <hip/hip_runtime.h>
#include <hip/hip_bf16.h>

typedef __attribute__((ext_vector_type(4))) float f32x4;
typedef __attribute__((ext_vector_type(8))) short bf16x8;
typedef unsigned short u16;

#define SEQ 2048
#define HID 1024
#define NROWS 16384

// ---------- helpers ----------
__device__ __forceinline__ float b2f(u16 u) {
    union { float f; unsigned i; } x; x.i = ((unsigned)u) << 16; return x.f;
}
__device__ __forceinline__ u16 f2b(float f) {
    unsigned x = __float_as_uint(f);
    return (u16)((x + 0x7fffu + ((x >> 16) & 1u)) >> 16);
}
__device__ __forceinline__ void gload16(const u16* g, u16* l) {
    __builtin_amdgcn_global_load_lds(
        (const __attribute__((address_space(1))) void*)g,
        (__attribute__((address_space(3))) void*)l,
        16, 0, 0);
}

// ---------- fp32 -> bf16 convert ----------
__global__ __launch_bounds__(256)
void cvt_kernel(const float* __restrict__ src, u16* __restrict__ dst, int n) {
    int base = (blockIdx.x * 256 + threadIdx.x) * 4;
    if (base < n) {
        float4 v = *(const float4*)&src[base];
        ushort4 o;
        o.x = f2b(v.x); o.y = f2b(v.y); o.z = f2b(v.z); o.w = f2b(v.w);
        *(ushort4*)&dst[base] = o;
    }
}

// ---------- GEMM: C = A @ B^T (+bias)*scale (+resid) ----------
// 256x256 tile, BK=64, 512 thr (8 waves 2Mx4N), per-wave 128x64 out.
// 8-phase schedule (T3+T4+T5): per K-tile 4 phases = (m-half x ks), each
// {ds_read subtile | stage 1 half-tile | bar | lgkmcnt(0) | setprio MFMA | bar},
// counted vmcnt(2) only at ends of P1/P4 (never 0 in main loop).
// Stage halves: h1=A quarters{0,2}, h2=B rows0-127, h3=B rows128-255,
// h4=A quarters{1,3}  (quarter q = 2*wm+mh rows, so phase-mh needs match).
// LDS XOR-swizzle (T2, rule 21): linear gload_lds dest + inverse-swizzled
// global source col + same XOR on ds_read.
template<int OUTMODE>
__global__ __launch_bounds__(512, 2)
void gemm_bt_kernel(const u16* __restrict__ A, const u16* __restrict__ B,
                    void* __restrict__ C,
                    const float* __restrict__ bias,
                    const float* __restrict__ resid,
                    float scale, int K,
                    long long sA, long long sB, long long sC,
                    int ldc)
{
    // ---- XCD-bijective block swizzle (T1); all grids have nwg % 8 == 0.
    const unsigned nwg = gridDim.x * gridDim.y * gridDim.z;
    const unsigned bid = blockIdx.x + gridDim.x * (blockIdx.y + gridDim.y * blockIdx.z);
    const unsigned work = (bid & 7u) * (nwg >> 3) + (bid >> 3);
    const unsigned bx = work % gridDim.x;
    const unsigned rem = work / gridDim.x;
    const unsigned by = rem % gridDim.y;
    const unsigned bz = rem / gridDim.y;

    A += (long long)bz * sA;
    B += (long long)bz * sB;

    const int tid  = threadIdx.x;
    const int lane = tid & 63;
    const int w    = tid >> 6;
    const int wm   = w >> 2;      // 0..1
    const int wn   = w & 3;       // 0..3
    const int fr   = lane & 15;
    const int kg   = lane >> 4;
    const int swz  = (fr & 7) << 3;

    const int m0 = by * 256;
    const int n0 = bx * 256;

    __shared__ u16 lds[65536];    // 2 buffers x (A 256x64 + B 256x64)

    f32x4 acc[8][4] = {};
    bf16x8 bA[4], bB[4];

    const int sr  = tid >> 3;             // 0..63
    const int sc8 = (tid & 7) << 3;       // u16 chunk col in LDS
    const int scb = sc8 ^ ((sr & 7) << 3); // inverse-swizzled global col

    const int nk = K >> 6;

#define STAGE_A(tt, q01, bsel) { \
    const int kb_ = (tt) << 6; \
    u16* dst_ = &lds[(bsel) * 32768]; \
    { const int row_ = (q01) * 64 + sr; \
      gload16(A + (size_t)(m0 + row_) * K + kb_ + scb, &dst_[row_ * 64 + sc8]); } \
    { const int row_ = ((q01) + 2) * 64 + sr; \
      gload16(A + (size_t)(m0 + row_) * K + kb_ + scb, &dst_[row_ * 64 + sc8]); } }

#define STAGE_B(tt, h, bsel) { \
    const int kb_ = (tt) << 6; \
    u16* dst_ = &lds[(bsel) * 32768 + 16384]; \
    { const int row_ = (h) * 128 + sr; \
      gload16(B + (size_t)(n0 + row_) * K + kb_ + scb, &dst_[row_ * 64 + sc8]); } \
    { const int row_ = (h) * 128 + 64 + sr; \
      gload16(B + (size_t)(n0 + row_) * K + kb_ + scb, &dst_[row_ * 64 + sc8]); } }

#define READ_A(mh, ks) { const int cb_ = (((ks) << 5) | (kg << 3)) ^ swz; \
    _Pragma("unroll") for (int i_ = 0; i_ < 4; ++i_) \
      bA[i_] = *(const bf16x8*)&Alp[(wm * 128 + (mh) * 64 + i_ * 16 + fr) * 64 + cb_]; }

#define READ_B(ks) { const int cb_ = (((ks) << 5) | (kg << 3)) ^ swz; \
    _Pragma("unroll") for (int n_ = 0; n_ < 4; ++n_) \
      bB[n_] = *(const bf16x8*)&Blp[(wn * 64 + n_ * 16 + fr) * 64 + cb_]; }

#define MFMA_PH(mh) \
    _Pragma("unroll") for (int i_ = 0; i_ < 4; ++i_) \
      _Pragma("unroll") for (int n_ = 0; n_ < 4; ++n_) \
        acc[(mh)*4 + i_][n_] = __builtin_amdgcn_mfma_f32_16x16x32_bf16(bA[i_], bB[n_], acc[(mh)*4 + i_][n_], 0, 0, 0);

#define BAR()   __builtin_amdgcn_s_barrier()
#define LGKM0() { asm volatile("s_waitcnt lgkmcnt(0)" ::: "memory"); __builtin_amdgcn_sched_barrier(0); }
#define VM(n)   asm volatile("s_waitcnt vmcnt(" #n ")" ::: "memory")
#define PRIO1() __builtin_amdgcn_s_setprio(1)
#define PRIO0() __builtin_amdgcn_s_setprio(0)

    // prologue: tile 0, halves in issue order A0,B0,B1,A1
    STAGE_A(0, 0, 0); STAGE_B(0, 0, 0); STAGE_B(0, 1, 0); STAGE_A(0, 1, 0);
    VM(2); BAR();

    for (int t = 0; t < nk - 1; ++t) {
        const u16* Alp = &lds[(t & 1) * 32768];
        const u16* Blp = Alp + 16384;
        const int nb = (t + 1) & 1;
        // P1: mh0 ks0
        READ_B(0); READ_A(0, 0);
        STAGE_A(t + 1, 0, nb);
        BAR(); LGKM0();
        PRIO1(); MFMA_PH(0); PRIO0();
        VM(2); BAR();
        // P2: mh1 ks0
        READ_A(1, 0);
        STAGE_B(t + 1, 0, nb);
        BAR(); LGKM0();
        PRIO1(); MFMA_PH(1); PRIO0();
        BAR();
        // P3: mh0 ks1
        READ_B(1); READ_A(0, 1);
        STAGE_B(t + 1, 1, nb);
        BAR(); LGKM0();
        PRIO1(); MFMA_PH(0); PRIO0();
        BAR();
        // P4: mh1 ks1
        READ_A(1, 1);
        STAGE_A(t + 1, 1, nb);
        BAR(); LGKM0();
        PRIO1(); MFMA_PH(1); PRIO0();
        VM(2); BAR();
    }
    {   // peeled last tile (no staging)
        const int t = nk - 1;
        const u16* Alp = &lds[(t & 1) * 32768];
        const u16* Blp = Alp + 16384;
        READ_B(0); READ_A(0, 0);
        BAR(); LGKM0();
        PRIO1(); MFMA_PH(0); PRIO0();
        VM(0); BAR();
        READ_A(1, 0);
        BAR(); LGKM0();
        PRIO1(); MFMA_PH(1); PRIO0();
        BAR();
        READ_B(1); READ_A(0, 1);
        BAR(); LGKM0();
        PRIO1(); MFMA_PH(0); PRIO0();
        BAR();
        READ_A(1, 1);
        BAR(); LGKM0();
        PRIO1(); MFMA_PH(1); PRIO0();
        BAR();   // gates LDS reuse by epilogue
    }

    // ---- coalesced epilogues via per-wave LDS transpose ----
    const int cc = lane & 15;
    const int rg = lane >> 4;

    if constexpr (OUTMODE == 0 || OUTMODE == 2) {
        float* ep = (float*)lds + w * 1088;   // [16][68] f32 per wave
        const int rcol = cc * 4;              // readback col 0..63
        float4 b4 = make_float4(0.f, 0.f, 0.f, 0.f);
        if (bias) b4 = *(const float4*)&bias[n0 + wn * 64 + rcol];
#pragma unroll
        for (int m = 0; m < 8; ++m) {
#pragma unroll
            for (int n = 0; n < 4; ++n)
#pragma unroll
                for (int r = 0; r < 4; ++r)
                    ep[(rg * 4 + r) * 68 + n * 16 + cc] = acc[m][n][r];
            LGKM0();
#pragma unroll
            for (int j = 0; j < 4; ++j) {
                const int row = j * 4 + rg;
                float4 v = *(const float4*)&ep[row * 68 + rcol];
                const int gr = m0 + wm * 128 + m * 16 + row;
                if constexpr (OUTMODE == 0) {
                    u16* Cb = (u16*)C + (long long)bz * sC;
                    ushort4 pk;
                    pk.x = f2b((v.x + b4.x) * scale);
                    pk.y = f2b((v.y + b4.y) * scale);
                    pk.z = f2b((v.z + b4.z) * scale);
                    pk.w = f2b((v.w + b4.w) * scale);
                    *(ushort4*)&Cb[(size_t)gr * ldc + n0 + wn * 64 + rcol] = pk;
                } else {
                    float* Cf = (float*)C;
                    size_t o = (size_t)gr * ldc + n0 + wn * 64 + rcol;
                    float4 rv = *(const float4*)&resid[o];
                    float4 ov;
                    ov.x = v.x + b4.x + rv.x;
                    ov.y = v.y + b4.y + rv.y;
                    ov.z = v.z + b4.z + rv.z;
                    ov.w = v.w + b4.w + rv.w;
                    *(float4*)&Cf[o] = ov;
                }
            }
            LGKM0();
        }
    } else {
        // OUTMODE 1: vT[b][hcol][s] — full-LDS bf16 transpose, XOR-swizzled
        u16* epW = &lds[w * 8192];            // [64 cols][128 s] u16 per wave
        const int colb = n0 + wn * 64;
        float bv4[4];
#pragma unroll
        for (int n = 0; n < 4; ++n) bv4[n] = bias ? bias[colb + n * 16 + cc] : 0.f;
        const int swc = (cc & 7) << 3;
#pragma unroll
        for (int n = 0; n < 4; ++n) {
            const int col = n * 16 + cc;
#pragma unroll
            for (int m = 0; m < 8; ++m)
#pragma unroll
                for (int rp = 0; rp < 2; ++rp) {
                    const int s = m * 16 + rg * 4 + rp * 2;
                    unsigned lo = f2b((acc[m][n][rp * 2]     + bv4[n]) * scale);
                    unsigned hi = f2b((acc[m][n][rp * 2 + 1] + bv4[n]) * scale);
                    *(unsigned*)&epW[col * 128 + (s ^ swc)] = lo | (hi << 16);
                }
        }
        LGKM0();
        const int b  = (m0 + wm * 128) >> 11;
        const int sb = (m0 + wm * 128) & 2047;
        u16* Vb = (u16*)C;
#pragma unroll
        for (int j = 0; j < 16; ++j) {
            const int col = j * 4 + rg;
            const int sc_ = (cc * 8) ^ ((col & 7) << 3);
            bf16x8 v = *(const bf16x8*)&epW[col * 128 + sc_];
            *(bf16x8*)&Vb[((size_t)b * HID + colb + col) * SEQ + sb + cc * 8] = v;
        }
    }
#undef STAGE_A
#undef STAGE_B
#undef READ_A
#undef READ_B
#undef MFMA_PH
#undef BAR
#undef LGKM0
#undef VM
#undef PRIO1
#undef PRIO0
}

// ---------- row softmax, in-place, bf16, row length 2048 ----------
__global__ __launch_bounds__(256)
void softmax_kernel(u16* __restrict__ sc) {
    const size_t row = blockIdx.x;
    u16* p = sc + row * 2048;
    const int tid = threadIdx.x;
    const int lane = tid & 63;
    const int w = tid >> 6;

    float v[8];
    ushort4 ua = *(const ushort4*)&p[tid * 8];
    ushort4 ub = *(const ushort4*)&p[tid * 8 + 4];
    v[0] = b2f(ua.x); v[1] = b2f(ua.y); v[2] = b2f(ua.z); v[3] = b2f(ua.w);
    v[4] = b2f(ub.x); v[5] = b2f(ub.y); v[6] = b2f(ub.z); v[7] = b2f(ub.w);

    float mx = v[0];
#pragma unroll
    for (int j = 1; j < 8; ++j) mx = fmaxf(mx, v[j]);
#pragma unroll
    for (int o = 32; o; o >>= 1) mx = fmaxf(mx, __shfl_xor(mx, o));

    __shared__ float red[8];
    if (!lane) red[w] = mx;
    __syncthreads();
    mx = fmaxf(fmaxf(red[0], red[1]), fmaxf(red[2], red[3]));

    float s = 0.f;
#pragma unroll
    for (int j = 0; j < 8; ++j) { v[j] = __expf(v[j] - mx); s += v[j]; }
#pragma unroll
    for (int o = 32; o; o >>= 1) s += __shfl_xor(s, o);
    if (!lane) red[4 + w] = s;
    __syncthreads();
    s = red[4] + red[5] + red[6] + red[7];
    float inv = 1.0f / s;

    ushort4 oa, ob;
    oa.x = f2b(v[0] * inv); oa.y = f2b(v[1] * inv); oa.z = f2b(v[2] * inv); oa.w = f2b(v[3] * inv);
    ob.x = f2b(v[4] * inv); ob.y = f2b(v[5] * inv); ob.z = f2b(v[6] * inv); ob.w = f2b(v[7] * inv);
    *(ushort4*)&p[tid * 8]     = oa;
    *(ushort4*)&p[tid * 8 + 4] = ob;
}

// ---------- in-place LayerNorm over rows of 1024 fp32 ----------
__global__ __launch_bounds__(256)
void layernorm_kernel(float* __restrict__ y,
                      const float* __restrict__ gamma,
                      const float* __restrict__ beta) {
    const size_t row = blockIdx.x;
    float* p = y + row * 1024;
    const int tid = threadIdx.x;
    const int lane = tid & 63;
    const int w = tid >> 6;

    float4 v = *(const float4*)&p[tid * 4];
    float s = v.x + v.y + v.z + v.w;
    float q = v.x * v.x + v.y * v.y + v.z * v.z + v.w * v.w;
#pragma unroll
    for (int o = 32; o; o >>= 1) { s += __shfl_xor(s, o); q += __shfl_xor(q, o); }

    __shared__ float red[16];
    if (!lane) { red[w] = s; red[8 + w] = q; }
    __syncthreads();
    s = red[0] + red[1] + red[2] + red[3];
    q = red[8] + red[9] + red[10] + red[11];

    const float mu  = s * (1.0f / 1024.0f);
    const float var = q * (1.0f / 1024.0f) - mu * mu;
    const float rs  = rsqrtf(var + 1e-5f);

    float4 g  = *(const float4*)&gamma[tid * 4];
    float4 be = *(const float4*)&beta[tid * 4];
    float4 o;
    o.x = (v.x - mu) * rs * g.x + be.x;
    o.y = (v.y - mu) * rs * g.y + be.y;
    o.z = (v.z - mu) * rs * g.z + be.z;
    o.w = (v.w - mu) * rs * g.w + be.w;
    *(float4*)&p[tid * 4] = o;
}

extern "C" void kernel_launch(void* const* d_in, const int* in_sizes, int n_in,
                              void* d_out, int out_size, void* d_ws, size_t ws_size,
                              hipStream_t stream) {
    const float* x     = (const float*)d_in[0];
    const float* Wq    = (const float*)d_in[1];
    const float* bq    = (const float*)d_in[2];
    const float* Wk    = (const float*)d_in[3];
    const float* bk    = (const float*)d_in[4];
    const float* Wv    = (const float*)d_in[5];
    const float* bv    = (const float*)d_in[6];
    const float* Wp    = (const float*)d_in[7];
    const float* bp    = (const float*)d_in[8];
    const float* gamma = (const float*)d_in[9];
    const float* beta  = (const float*)d_in[10];
    float* out = (float*)d_out;

    char* ws = (char*)d_ws;
    u16* xb     = (u16*)(ws + 0);
    u16* qb     = (u16*)(ws + 33554432);
    u16* kb     = (u16*)(ws + 67108864);
    u16* vT     = (u16*)(ws + 100663296);    // [8][1024][2048]
    u16* ctx    = (u16*)(ws + 134217728);
    u16* wqb    = (u16*)(ws + 167772160);
    u16* wkb    = (u16*)(ws + 169869312);
    u16* wvb    = (u16*)(ws + 171966464);
    u16* wpb    = (u16*)(ws + 174063616);
    u16* scores = (u16*)(ws + 176160768);

    cvt_kernel<<<16384, 256, 0, stream>>>(x,  xb,  NROWS * HID);
    cvt_kernel<<<1024, 256, 0, stream>>>(Wq, wqb, HID * HID);
    cvt_kernel<<<1024, 256, 0, stream>>>(Wk, wkb, HID * HID);
    cvt_kernel<<<1024, 256, 0, stream>>>(Wv, wvb, HID * HID);
    cvt_kernel<<<1024, 256, 0, stream>>>(Wp, wpb, HID * HID);

    dim3 blk(512);
    // q/k/v projections  (q folded with 1/sqrt(H)=1/32)
    gemm_bt_kernel<0><<<dim3(4, 64, 1), blk, 0, stream>>>(xb, wqb, qb, bq, nullptr, 0.03125f, HID, 0, 0, 0, HID);
    gemm_bt_kernel<0><<<dim3(4, 64, 1), blk, 0, stream>>>(xb, wkb, kb, bk, nullptr, 1.0f,     HID, 0, 0, 0, HID);
    gemm_bt_kernel<1><<<dim3(4, 64, 1), blk, 0, stream>>>(xb, wvb, vT, bv, nullptr, 1.0f,     HID, 0, 0, 0, 0);

    // scores = q' @ k^T  (per batch)
    gemm_bt_kernel<0><<<dim3(8, 8, 8), blk, 0, stream>>>(
        qb, kb, scores, nullptr, nullptr, 1.0f, HID,
        (long long)SEQ * HID, (long long)SEQ * HID, (long long)SEQ * SEQ, SEQ);

    softmax_kernel<<<NROWS, 256, 0, stream>>>(scores);

    // context = attn @ v   (B = vT, K-contiguous)
    gemm_bt_kernel<0><<<dim3(4, 8, 8), blk, 0, stream>>>(
        scores, vT, ctx, nullptr, nullptr, 1.0f, SEQ,
        (long long)SEQ * SEQ, (long long)HID * SEQ, (long long)SEQ * HID, HID);

    // out = ctx @ Wp^T + bp + x  (fp32 into d_out)
    gemm_bt_kernel<2><<<dim3(4, 64, 1), blk, 0, stream>>>(ctx, wpb, out, bp, x, 1.0f, HID, 0, 0, 0, HID);

    layernorm_kernel<<<NROWS, 256, 0, stream>>>(out, gamma, beta);
}